// Round 3
// baseline (116.799 us; speedup 1.0000x reference)
//
#include <hip/hip_runtime.h>

#define B_ 16
#define R_ 4
#define S_ 4
#define T_ 14
#define F_ 2048
constexpr int P_ = F_ / 4;   // vector-of-4 elements along f

typedef float vf __attribute__((ext_vector_type(4)));

struct cplx { vf re, im; };

__device__ __forceinline__ vf vsp(float s){ vf r; r.x = s; r.y = s; r.z = s; r.w = s; return r; }
__device__ __forceinline__ vf vrcp(vf x){
    vf r; r.x = __builtin_amdgcn_rcpf(x.x); r.y = __builtin_amdgcn_rcpf(x.y);
    r.z = __builtin_amdgcn_rcpf(x.z); r.w = __builtin_amdgcn_rcpf(x.w); return r;
}
__device__ __forceinline__ vf vrsq(vf x){
    vf r; r.x = __builtin_amdgcn_rsqf(x.x); r.y = __builtin_amdgcn_rsqf(x.y);
    r.z = __builtin_amdgcn_rsqf(x.z); r.w = __builtin_amdgcn_rsqf(x.w); return r;
}

__device__ __forceinline__ cplx cmul(cplx a, cplx b) {
    return {a.re*b.re - a.im*b.im, a.re*b.im + a.im*b.re};
}
// conj(a) * b
__device__ __forceinline__ cplx cmulc(cplx a, cplx b) {
    return {a.re*b.re + a.im*b.im, a.re*b.im - a.im*b.re};
}
__device__ __forceinline__ cplx cadd(cplx a, cplx b){ return {a.re+b.re, a.im+b.im}; }
__device__ __forceinline__ cplx csub(cplx a, cplx b){ return {a.re-b.re, a.im-b.im}; }
__device__ __forceinline__ cplx cscale(cplx a, vf s){ return {a.re*s, a.im*s}; }
__device__ __forceinline__ cplx conjc(cplx a){ return {a.re, -a.im}; }
__device__ __forceinline__ vf cnorm(cplx a){ return a.re*a.re + a.im*a.im; }

__device__ __forceinline__ vf ntload(const vf* p){ return __builtin_nontemporal_load(p); }

__global__ __launch_bounds__(256) void sic_lmmse_kernel(
    const float* __restrict__ y_re_, const float* __restrict__ y_im_,
    const float* __restrict__ h_re_, const float* __restrict__ h_im_,
    const int* __restrict__ mask, const float* __restrict__ nv,
    float* __restrict__ out_)
{
    constexpr int BSTP = B_ * S_ * T_ * P_;   // one output plane, in vf units

    int idx = blockIdx.x * 256 + threadIdx.x; // N = 448*256 exactly
    int fv = idx % P_;
    int bt = idx / P_;
    int t  = bt % T_;
    int b  = bt / T_;

    const vf* y_re = (const vf*)y_re_;
    const vf* y_im = (const vf*)y_im_;
    const vf* h_re = (const vf*)h_re_;
    const vf* h_im = (const vf*)h_im_;
    vf*       out  = (vf*)out_;

    float no  = nv[0];
    vf    vno = vsp(no);

    int4 mi = ((const int4*)mask)[t * P_ + fv];
    vf m; m.x = (float)mi.x; m.y = (float)mi.y; m.z = (float)mi.z; m.w = (float)mi.w;

    // ---- explicit 2-stage load pipeline: issue ALL loads for r=0,1 then
    // r=2,3 before any gram compute, so >=20 16B loads/wave are in flight.
    cplx yA[2], hA[2][4];
    cplx yB[2], hB[2][4];
    #pragma unroll
    for (int r = 0; r < 2; r++) {
        int ybase = ((b * R_ + r) * T_ + t) * P_ + fv;
        yA[r].re = ntload(y_re + ybase);
        yA[r].im = ntload(y_im + ybase);
        #pragma unroll
        for (int s = 0; s < 4; s++) {
            int hbase = (((b * R_ + r) * S_ + s) * T_ + t) * P_ + fv;
            hA[r][s].re = ntload(h_re + hbase);
            hA[r][s].im = ntload(h_im + hbase);
        }
    }
    #pragma unroll
    for (int r = 2; r < 4; r++) {
        int ybase = ((b * R_ + r) * T_ + t) * P_ + fv;
        yB[r - 2].re = ntload(y_re + ybase);
        yB[r - 2].im = ntload(y_im + ybase);
        #pragma unroll
        for (int s = 0; s < 4; s++) {
            int hbase = (((b * R_ + r) * S_ + s) * T_ + t) * P_ + fv;
            hB[r - 2][s].re = ntload(h_re + hbase);
            hB[r - 2][s].im = ntload(h_im + hbase);
        }
    }

    // ---- gram (lower off-diag + real diag) and z = H^H y ----
    cplx go[4][4];          // off-diagonal lower entries, s > u
    vf   gd[4];             // real diagonal
    cplx z[4];
    #pragma unroll
    for (int i = 0; i < 4; i++) {
        z[i]  = { vsp(0.f), vsp(0.f) };
        gd[i] = vsp(0.f);
        #pragma unroll
        for (int j = 0; j < i; j++) go[i][j] = { vsp(0.f), vsp(0.f) };
    }

    #pragma unroll
    for (int r = 0; r < 2; r++) {
        cplx yr = yA[r];
        #pragma unroll
        for (int s = 0; s < 4; s++) {
            z[s]  = cadd(z[s], cmulc(hA[r][s], yr));
            gd[s] = gd[s] + cnorm(hA[r][s]);
            #pragma unroll
            for (int u = 0; u < s; u++)
                go[s][u] = cadd(go[s][u], cmulc(hA[r][s], hA[r][u]));
        }
    }
    #pragma unroll
    for (int r = 0; r < 2; r++) {
        cplx yr = yB[r];
        #pragma unroll
        for (int s = 0; s < 4; s++) {
            z[s]  = cadd(z[s], cmulc(hB[r][s], yr));
            gd[s] = gd[s] + cnorm(hB[r][s]);
            #pragma unroll
            for (int u = 0; u < s; u++)
                go[s][u] = cadd(go[s][u], cmulc(hB[r][s], hB[r][u]));
        }
    }

    // ---- reverse Cholesky: A = U U^H, U upper triangular, real diag ----
    // Every trailing block satisfies A[k:,k:] = U[k:,k:] U[k:,k:]^H, so one
    // factorization serves all 4 SIC steps (no explicit inverse, no downdates).
    cplx U[4][4];           // upper off-diagonal entries U[j][i], j < i
    vf dinv[4];             // 1 / U[i][i]
    #pragma unroll
    for (int i = 3; i >= 0; i--) {
        vf dd = gd[i] + vno;
        #pragma unroll
        for (int p = i + 1; p < 4; p++) dd = dd - cnorm(U[i][p]);
        dinv[i] = vrsq(dd);                 // dd >= no > 0 (PD Schur complement)
        #pragma unroll
        for (int j = i - 1; j >= 0; j--) {
            cplx s = conjc(go[i][j]);       // A[j][i] = conj(A[i][j])
            #pragma unroll
            for (int p = i + 1; p < 4; p++)
                s = csub(s, cmul(U[j][p], conjc(U[i][p])));
            U[j][i] = cscale(s, dinv[i]);
        }
    }

    // ---- SIC loop ----
    // e_k   = inv(A[k:,k:])_00            = dinv[k]^2
    // xz_k  = (inv(A[k:,k:]) zc[k:])_0    = w[k] * dinv[k],  U[k:,k:] w = zc[k:]
    cplx zc[4];
    #pragma unroll
    for (int j = 0; j < 4; j++) zc[j] = z[j];

    #pragma unroll
    for (int k = 0; k < 4; k++) {
        // back-substitution (bottom-up) against current residual zc
        cplx w[4];
        #pragma unroll
        for (int i = 3; i >= k; i--) {
            cplx s = zc[i];
            #pragma unroll
            for (int p = i + 1; p < 4; p++)
                s = csub(s, cmul(U[i][p], w[p]));
            w[i] = cscale(s, dinv[i]);
        }

        vf e    = dinv[k] * dinv[k];        // Ainv[k,k], real > 0
        vf d    = vsp(1.0f) - vno * e;      // (Ainv gram0)_kk = 1 - no*Ainv_kk
        vf drcp = vrcp(d);
        cplx xk = cscale(w[k], dinv[k] * drcp);
        vf ne   = vno * e * drcp;           // (1-d)/d

        int obase = ((b * S_ + k) * T_ + t) * P_ + fv;
        __builtin_nontemporal_store(xk.re * m, &out[obase]);
        __builtin_nontemporal_store(xk.im * m, &out[BSTP + obase]);
        __builtin_nontemporal_store(ne * m,    &out[2 * BSTP + obase]);

        if (k < 3) {
            #pragma unroll
            for (int j = k + 1; j < 4; j++)
                zc[j] = csub(zc[j], cmul(go[j][k], xk));
        }
    }
}

extern "C" void kernel_launch(void* const* d_in, const int* in_sizes, int n_in,
                              void* d_out, int out_size, void* d_ws, size_t ws_size,
                              hipStream_t stream) {
    const float* y_re = (const float*)d_in[0];
    const float* y_im = (const float*)d_in[1];
    const float* h_re = (const float*)d_in[2];
    const float* h_im = (const float*)d_in[3];
    const int*   mask = (const int*)  d_in[4];
    const float* nv   = (const float*)d_in[5];
    float* out = (float*)d_out;

    constexpr int N = B_ * T_ * P_;          // 114,688 = 448 * 256
    int threads = 256;
    int blocks  = N / threads;
    hipLaunchKernelGGL(sic_lmmse_kernel, dim3(blocks), dim3(threads), 0, stream,
                       y_re, y_im, h_re, h_im, mask, nv, out);
}

// Round 4
// 109.473 us; speedup vs baseline: 1.0669x; 1.0669x over previous
//
#include <hip/hip_runtime.h>

#define B_ 16
#define R_ 4
#define S_ 4
#define T_ 14
#define F_ 2048
constexpr int P_ = F_ / 4;   // vector-of-4 elements along f

typedef float vf __attribute__((ext_vector_type(4)));

struct cplx { vf re, im; };

__device__ __forceinline__ vf vsp(float s){ vf r; r.x = s; r.y = s; r.z = s; r.w = s; return r; }
__device__ __forceinline__ vf vrcp(vf x){
    vf r; r.x = __builtin_amdgcn_rcpf(x.x); r.y = __builtin_amdgcn_rcpf(x.y);
    r.z = __builtin_amdgcn_rcpf(x.z); r.w = __builtin_amdgcn_rcpf(x.w); return r;
}
__device__ __forceinline__ vf vrsq(vf x){
    vf r; r.x = __builtin_amdgcn_rsqf(x.x); r.y = __builtin_amdgcn_rsqf(x.y);
    r.z = __builtin_amdgcn_rsqf(x.z); r.w = __builtin_amdgcn_rsqf(x.w); return r;
}

__device__ __forceinline__ cplx cmul(cplx a, cplx b) {
    return {a.re*b.re - a.im*b.im, a.re*b.im + a.im*b.re};
}
// conj(a) * b
__device__ __forceinline__ cplx cmulc(cplx a, cplx b) {
    return {a.re*b.re + a.im*b.im, a.re*b.im - a.im*b.re};
}
__device__ __forceinline__ cplx cadd(cplx a, cplx b){ return {a.re+b.re, a.im+b.im}; }
__device__ __forceinline__ cplx csub(cplx a, cplx b){ return {a.re-b.re, a.im-b.im}; }
__device__ __forceinline__ cplx cscale(cplx a, vf s){ return {a.re*s, a.im*s}; }
__device__ __forceinline__ cplx conjc(cplx a){ return {a.re, -a.im}; }
__device__ __forceinline__ vf cnorm(cplx a){ return a.re*a.re + a.im*a.im; }

__global__ __launch_bounds__(256) void sic_lmmse_kernel(
    const float* __restrict__ y_re_, const float* __restrict__ y_im_,
    const float* __restrict__ h_re_, const float* __restrict__ h_im_,
    const int* __restrict__ mask, const float* __restrict__ nv,
    float* __restrict__ out_)
{
    constexpr int BSTP = B_ * S_ * T_ * P_;   // one output plane, in vf units

    int idx = blockIdx.x * 256 + threadIdx.x; // N = 448*256 exactly
    int fv = idx % P_;
    int bt = idx / P_;
    int t  = bt % T_;
    int b  = bt / T_;

    const vf* y_re = (const vf*)y_re_;
    const vf* y_im = (const vf*)y_im_;
    const vf* h_re = (const vf*)h_re_;
    const vf* h_im = (const vf*)h_im_;
    vf*       out  = (vf*)out_;

    float no  = nv[0];
    vf    vno = vsp(no);

    int4 mi = ((const int4*)mask)[t * P_ + fv];
    vf m; m.x = (float)mi.x; m.y = (float)mi.y; m.z = (float)mi.z; m.w = (float)mi.w;

    // ---- gram (lower off-diag + real diag) and z = H^H y ----
    cplx go[4][4];          // off-diagonal lower entries, s > u
    vf   gd[4];             // real diagonal
    cplx z[4];
    #pragma unroll
    for (int i = 0; i < 4; i++) {
        z[i]  = { vsp(0.f), vsp(0.f) };
        gd[i] = vsp(0.f);
        #pragma unroll
        for (int j = 0; j < i; j++) go[i][j] = { vsp(0.f), vsp(0.f) };
    }

    #pragma unroll
    for (int r = 0; r < 4; r++) {
        int ybase = ((b * R_ + r) * T_ + t) * P_ + fv;
        cplx yr = { y_re[ybase], y_im[ybase] };
        cplx hr[4];
        #pragma unroll
        for (int s = 0; s < 4; s++) {
            int hbase = (((b * R_ + r) * S_ + s) * T_ + t) * P_ + fv;
            hr[s] = { h_re[hbase], h_im[hbase] };
        }
        #pragma unroll
        for (int s = 0; s < 4; s++) {
            z[s]  = cadd(z[s], cmulc(hr[s], yr));
            gd[s] = gd[s] + hr[s].re * hr[s].re + hr[s].im * hr[s].im;
            #pragma unroll
            for (int u = 0; u < s; u++)
                go[s][u] = cadd(go[s][u], cmulc(hr[s], hr[u]));
        }
    }

    // ---- reverse Cholesky: A = U U^H, U upper triangular, real diag ----
    // Every trailing block satisfies A[k:,k:] = U[k:,k:] U[k:,k:]^H, so one
    // factorization serves all 4 SIC steps (no explicit inverse, no downdates).
    cplx U[4][4];           // upper off-diagonal entries U[j][i], j < i
    vf dinv[4];             // 1 / U[i][i]
    #pragma unroll
    for (int i = 3; i >= 0; i--) {
        vf dd = gd[i] + vno;
        #pragma unroll
        for (int p = i + 1; p < 4; p++) dd = dd - cnorm(U[i][p]);
        dinv[i] = vrsq(dd);                 // dd >= no > 0 (PD Schur complement)
        #pragma unroll
        for (int j = i - 1; j >= 0; j--) {
            cplx s = conjc(go[i][j]);       // A[j][i] = conj(A[i][j])
            #pragma unroll
            for (int p = i + 1; p < 4; p++)
                s = csub(s, cmul(U[j][p], conjc(U[i][p])));
            U[j][i] = cscale(s, dinv[i]);
        }
    }

    // ---- SIC loop ----
    // e_k   = inv(A[k:,k:])_00            = dinv[k]^2
    // xz_k  = (inv(A[k:,k:]) zc[k:])_0    = w[k] * dinv[k],  U[k:,k:] w = zc[k:]
    cplx zc[4];
    #pragma unroll
    for (int j = 0; j < 4; j++) zc[j] = z[j];

    #pragma unroll
    for (int k = 0; k < 4; k++) {
        // back-substitution (bottom-up) against current residual zc
        cplx w[4];
        #pragma unroll
        for (int i = 3; i >= k; i--) {
            cplx s = zc[i];
            #pragma unroll
            for (int p = i + 1; p < 4; p++)
                s = csub(s, cmul(U[i][p], w[p]));
            w[i] = cscale(s, dinv[i]);
        }

        vf e    = dinv[k] * dinv[k];        // Ainv[k,k], real > 0
        vf d    = vsp(1.0f) - vno * e;      // (Ainv gram0)_kk = 1 - no*Ainv_kk
        vf drcp = vrcp(d);
        cplx xk = cscale(w[k], dinv[k] * drcp);
        vf ne   = vno * e * drcp;           // (1-d)/d

        int obase = ((b * S_ + k) * T_ + t) * P_ + fv;
        out[obase]            = xk.re * m;
        out[BSTP + obase]     = xk.im * m;
        out[2 * BSTP + obase] = ne * m;

        if (k < 3) {
            #pragma unroll
            for (int j = k + 1; j < 4; j++)
                zc[j] = csub(zc[j], cmul(go[j][k], xk));
        }
    }
}

extern "C" void kernel_launch(void* const* d_in, const int* in_sizes, int n_in,
                              void* d_out, int out_size, void* d_ws, size_t ws_size,
                              hipStream_t stream) {
    const float* y_re = (const float*)d_in[0];
    const float* y_im = (const float*)d_in[1];
    const float* h_re = (const float*)d_in[2];
    const float* h_im = (const float*)d_in[3];
    const int*   mask = (const int*)  d_in[4];
    const float* nv   = (const float*)d_in[5];
    float* out = (float*)d_out;

    constexpr int N = B_ * T_ * P_;          // 114,688 = 448 * 256
    int threads = 256;
    int blocks  = N / threads;
    hipLaunchKernelGGL(sic_lmmse_kernel, dim3(blocks), dim3(threads), 0, stream,
                       y_re, y_im, h_re, h_im, mask, nv, out);
}